// Round 4
// baseline (4985.630 us; speedup 1.0000x reference)
//
#include <hip/hip_runtime.h>

#define SEQ   512
#define BATCH 64
#define DIN   512
#define DH    512
#define KTOT  1024
#define NWG   128
#define NTH   256
#define HBUF_BYTES 65536   // 4 mt * 16 kt * 64 lanes * 16 B

// ws layout (bytes): [0,1024) legacy; [1024,17408) arrival flags (128 x 128B);
// [20480,21504) broadcast epoch (8 x 128B); [32768, ...) h ping-pong buffers.
#define FLAGS_OFF 1024
#define BCAST_OFF 20480
#define HBASE_OFF 32768
#define FLAG_STRIDE 32   // uints (128 B)

typedef __attribute__((ext_vector_type(8))) short short8;   // 8 x bf16
typedef __attribute__((ext_vector_type(4))) float f32x4;

__device__ __forceinline__ float sig_(float v) { return 1.0f / (1.0f + __expf(-v)); }

// fp32 -> bf16 RNE (finite inputs), dependency-free
__device__ __forceinline__ unsigned short f2bf(float f) {
    unsigned int u = __float_as_uint(f);
    return (unsigned short)((u + 0x7fffu + ((u >> 16) & 1u)) >> 16);
}

__device__ __forceinline__ short8 cvt8(float4 lo, float4 hi) {
    short8 r;
    r[0] = (short)f2bf(lo.x); r[1] = (short)f2bf(lo.y);
    r[2] = (short)f2bf(lo.z); r[3] = (short)f2bf(lo.w);
    r[4] = (short)f2bf(hi.x); r[5] = (short)f2bf(hi.y);
    r[6] = (short)f2bf(hi.z); r[7] = (short)f2bf(hi.w);
    return r;
}

__device__ __forceinline__ unsigned int ld_flag(const unsigned int* p) {
    return __hip_atomic_load(p, __ATOMIC_RELAXED, __HIP_MEMORY_SCOPE_AGENT);
}
__device__ __forceinline__ void st_flag(unsigned int* p, unsigned int v) {
    __hip_atomic_store(p, v, __ATOMIC_RELAXED, __HIP_MEMORY_SCOPE_AGENT);
}

// Persistent MFMA LSTM, round 4: round 3 + decontended hierarchical barrier.
// 128 WGs x 256 threads (4 waves). WG owns 4 h-columns across 4 gates (N=16).
// Wave = M-tile. Weights in 128 VGPR/lane (loaded once). h crosses WGs as
// bf16 A-fragments in a ws ping-pong buffer via sc1 (RELAXED+AGENT) atomics.
// Barrier: per-WG flag (own cacheline) -> WG0/wave0 vector-polls all 128
// flags -> broadcast epoch to 8 spread lines -> WGs poll their line.
__global__ __launch_bounds__(NTH, 1)
void lstm_mfma(const float* __restrict__ x,
               const float* __restrict__ Wf, const float* __restrict__ bfp,
               const float* __restrict__ Wi, const float* __restrict__ bip,
               const float* __restrict__ Wg, const float* __restrict__ bgp,
               const float* __restrict__ Wo, const float* __restrict__ bop,
               float* __restrict__ out,
               unsigned int* __restrict__ ws_u32)
{
    const int tid = threadIdx.x;
    const int l   = tid & 63;
    const int mt  = tid >> 6;              // wave = M-tile (batches mt*16..+15)
    const int wg  = blockIdx.x;
    const int j0  = wg * 4;

    const int n    = l & 15;               // output row (gate*4 + jc) in C cols
    const int khi  = l >> 4;               // k-group for A/B fragments

    unsigned int* const flags = ws_u32 + FLAGS_OFF / 4;
    unsigned int* const bcast = ws_u32 + BCAST_OFF / 4;
    char* const hbase = (char*)ws_u32 + HBASE_OFF;

    // ---- load the 32 B-fragments (weights, bf16) into VGPRs, once ----------
    const float* Wn = (n < 8) ? ((n < 4) ? Wf : Wi) : ((n < 12) ? Wg : Wo);
    const float* wrow = Wn + (size_t)(j0 + (n & 3)) * KTOT + khi * 8;
    short8 Bfr[32];
    #pragma unroll
    for (int kt = 0; kt < 32; ++kt) {
        const float4 lo = *(const float4*)(wrow + kt * 32);
        const float4 hi = *(const float4*)(wrow + kt * 32 + 4);
        Bfr[kt] = cvt8(lo, hi);
    }
    const float biasn = ((n < 8) ? ((n < 4) ? bfp : bip)
                                 : ((n < 12) ? bgp : bop))[j0 + (n & 3)];

    // c-state: 4 values per jc-lane (lanes with (l>>2)&3 == 0)
    float cst0 = 0.f, cst1 = 0.f, cst2 = 0.f, cst3 = 0.f;

    float* const hx_out = out + (size_t)SEQ * BATCH * DH;
    float* const cx_out = hx_out + (size_t)BATCH * DH;

    // producer-side h-fragment coordinates (constant over t)
    const int kth    = wg >> 3;                         // h k-tile 0..15
    const int e_h    = (wg & 1) * 4 + (l & 3);          // elem 0..7 (jc-lanes)
    const int lane_f_base = ((wg & 7) >> 1) << 4;       // hi<<4

    const float* xrow_base = x + (size_t)(mt * 16 + (l & 15)) * DIN + khi * 8;

    for (int t = 0; t < SEQ; ++t) {
        f32x4 acc = {0.f, 0.f, 0.f, 0.f};

        // ---------- phase X: x[t] contribution (barrier-independent) -------
        {
            const float* xr = xrow_base + (size_t)t * BATCH * DIN;
            #pragma unroll
            for (int kt = 0; kt < 16; ++kt) {
                const float4 lo = *(const float4*)(xr + kt * 32);
                const float4 hi = *(const float4*)(xr + kt * 32 + 4);
                const short8 a = cvt8(lo, hi);
                acc = __builtin_amdgcn_mfma_f32_16x16x32_bf16(a, Bfr[kt], acc, 0, 0, 0);
            }
        }

        if (t > 0) {
            // ------ hierarchical epoch barrier (no contended atomics) ------
            const unsigned int target = (unsigned int)t;
            if (wg == 0) {
                if (tid < 64) {          // wave 0: vector-poll all 128 flags
                    const unsigned int* f0p = flags + (size_t)l * FLAG_STRIDE;
                    const unsigned int* f1p = flags + (size_t)(64 + l) * FLAG_STRIDE;
                    for (;;) {
                        const unsigned int f0 = ld_flag(f0p);
                        const unsigned int f1 = ld_flag(f1p);
                        if (__all(f0 >= target && f1 >= target)) break;
                        __builtin_amdgcn_s_sleep(1);
                    }
                    if (l < 8) st_flag(bcast + (size_t)l * FLAG_STRIDE, target);
                }
            } else {
                if (tid == 0) {
                    const unsigned int* bp = bcast + (size_t)(wg & 7) * FLAG_STRIDE;
                    while (ld_flag(bp) < target) __builtin_amdgcn_s_sleep(1);
                }
            }
            __syncthreads();

            // ---------- phase H: h[t-1] via sc1 loads ----------------------
            const unsigned long long* hp =
                (const unsigned long long*)(hbase + ((t & 1) ^ 1) * HBUF_BYTES)
                + ((size_t)(mt * 16) * 64 + l) * 2;
            unsigned long long hv[32];
            #pragma unroll
            for (int kt = 0; kt < 16; ++kt) {
                hv[2 * kt]     = __hip_atomic_load(hp + kt * 128,     __ATOMIC_RELAXED,
                                                   __HIP_MEMORY_SCOPE_AGENT);
                hv[2 * kt + 1] = __hip_atomic_load(hp + kt * 128 + 1, __ATOMIC_RELAXED,
                                                   __HIP_MEMORY_SCOPE_AGENT);
            }
            #pragma unroll
            for (int kt = 0; kt < 16; ++kt) {
                union { unsigned long long u[2]; short8 v; } U;
                U.u[0] = hv[2 * kt];
                U.u[1] = hv[2 * kt + 1];
                acc = __builtin_amdgcn_mfma_f32_16x16x32_bf16(U.v, Bfr[16 + kt], acc, 0, 0, 0);
            }
        }

        // ---------- epilogue: gates, state update, stores ------------------
        const float p0 = acc[0] + biasn;
        const float p1 = acc[1] + biasn;
        const float p2 = acc[2] + biasn;
        const float p3 = acc[3] + biasn;

        const float i0 = __shfl_xor(p0, 4), g0 = __shfl_xor(p0, 8), o0 = __shfl_xor(p0, 12);
        const float i1 = __shfl_xor(p1, 4), g1 = __shfl_xor(p1, 8), o1 = __shfl_xor(p1, 12);
        const float i2 = __shfl_xor(p2, 4), g2 = __shfl_xor(p2, 8), o2 = __shfl_xor(p2, 12);
        const float i3 = __shfl_xor(p3, 4), g3 = __shfl_xor(p3, 8), o3 = __shfl_xor(p3, 12);

        if (((l >> 2) & 3) == 0) {          // jc-lanes: l&15 in 0..3
            const int jc = l & 3;
            const int j  = j0 + jc;
            const int b0 = mt * 16 + (l >> 4) * 4;   // q adds 0..3
            char* const wb = hbase + (t & 1) * HBUF_BYTES;

            float hq[4];
            cst0 = fmaf(sig_(p0), cst0, sig_(i0) * tanhf(g0)); hq[0] = sig_(o0) * tanhf(cst0);
            cst1 = fmaf(sig_(p1), cst1, sig_(i1) * tanhf(g1)); hq[1] = sig_(o1) * tanhf(cst1);
            cst2 = fmaf(sig_(p2), cst2, sig_(i2) * tanhf(g2)); hq[2] = sig_(o2) * tanhf(cst2);
            cst3 = fmaf(sig_(p3), cst3, sig_(i3) * tanhf(g3)); hq[3] = sig_(o3) * tanhf(cst3);

            #pragma unroll
            for (int q = 0; q < 4; ++q) {
                const int b = b0 + q;
                out[((size_t)t * BATCH + b) * DH + j] = hq[q];
                unsigned short* hp_w = (unsigned short*)
                    (wb + (((size_t)(mt * 16 + kth) * 64
                            + (lane_f_base | (b & 15))) << 4) + e_h * 2);
                __hip_atomic_store(hp_w, f2bf(hq[q]), __ATOMIC_RELAXED,
                                   __HIP_MEMORY_SCOPE_AGENT);
            }
            if (t == SEQ - 1) {
                #pragma unroll
                for (int q = 0; q < 4; ++q) {
                    const int b = b0 + q;
                    hx_out[(size_t)b * DH + j] = hq[q];
                }
                cx_out[(size_t)b0 * DH + j]       = cst0;
                cx_out[(size_t)(b0 + 1) * DH + j] = cst1;
                cx_out[(size_t)(b0 + 2) * DH + j] = cst2;
                cx_out[(size_t)(b0 + 3) * DH + j] = cst3;
            }
        }

        if (t < SEQ - 1) {
            __syncthreads();   // all waves drain vmcnt(0): h stores at LLC
            if (tid == 0) st_flag(flags + (size_t)wg * FLAG_STRIDE,
                                  (unsigned int)(t + 1));
        }
    }
}

extern "C" void kernel_launch(void* const* d_in, const int* in_sizes, int n_in,
                              void* d_out, int out_size, void* d_ws, size_t ws_size,
                              hipStream_t stream)
{
    const float* x  = (const float*)d_in[0];
    const float* Wf = (const float*)d_in[1];
    const float* bf = (const float*)d_in[2];
    const float* Wi = (const float*)d_in[3];
    const float* bi = (const float*)d_in[4];
    const float* Wg = (const float*)d_in[5];
    const float* bg = (const float*)d_in[6];
    const float* Wo = (const float*)d_in[7];
    const float* bo = (const float*)d_in[8];
    float* out = (float*)d_out;

    // flags + bcast must be 0 at every launch (ws poisoned 0xAA once, never
    // re-poisoned). h buffers need no init: buf[t&1] written before read.
    hipMemsetAsync(d_ws, 0, HBASE_OFF, stream);

    lstm_mfma<<<NWG, NTH, 0, stream>>>(x, Wf, bf, Wi, bi, Wg, bg, Wo, bo,
                                       out, (unsigned int*)d_ws);
}

// Round 5
// 4823.013 us; speedup vs baseline: 1.0337x; 1.0337x over previous
//
#include <hip/hip_runtime.h>

#define SEQ   512
#define BATCH 64
#define DIN   512
#define DH    512
#define KTOT  1024
#define NWG   128
#define NTH   256
#define HBUF_BYTES 65536   // 4 mt * 16 kt * 64 lanes * 16 B

// ws layout (bytes):
//   [0, 65536)          per-(mt,wg) tag flags: offset (mt*128 + wg)*128
//   [65536, 65536+128K) h ping-pong buffers (2 x 64 KB)
#define HBASE_OFF 65536
#define FLAG_STRIDE 32   // uints (128 B)

typedef __attribute__((ext_vector_type(8))) short short8;   // 8 x bf16
typedef __attribute__((ext_vector_type(4))) float f32x4;

__device__ __forceinline__ float sig_(float v) { return 1.0f / (1.0f + __expf(-v)); }

// fp32 -> bf16 RNE (finite inputs), dependency-free
__device__ __forceinline__ unsigned short f2bf(float f) {
    unsigned int u = __float_as_uint(f);
    return (unsigned short)((u + 0x7fffu + ((u >> 16) & 1u)) >> 16);
}

__device__ __forceinline__ short8 cvt8(float4 lo, float4 hi) {
    short8 r;
    r[0] = (short)f2bf(lo.x); r[1] = (short)f2bf(lo.y);
    r[2] = (short)f2bf(lo.z); r[3] = (short)f2bf(lo.w);
    r[4] = (short)f2bf(hi.x); r[5] = (short)f2bf(hi.y);
    r[6] = (short)f2bf(hi.z); r[7] = (short)f2bf(hi.w);
    return r;
}

__device__ __forceinline__ unsigned int ld_flag(const unsigned int* p) {
    return __hip_atomic_load(p, __ATOMIC_RELAXED, __HIP_MEMORY_SCOPE_AGENT);
}
__device__ __forceinline__ void st_flag(unsigned int* p, unsigned int v) {
    __hip_atomic_store(p, v, __ATOMIC_RELAXED, __HIP_MEMORY_SCOPE_AGENT);
}

// Persistent MFMA LSTM, round 5: barrier-free per-wave dataflow.
// 128 WGs x 256 threads; waves are fully independent (no LDS, no syncthreads).
// Wave (wg, mt) produces h[j0..j0+3] for batches mt*16..+15 each step, stores
// them (sc1) in A-fragment layout, drains vmcnt, then publishes tag t+1 to its
// own 128B flag line. A consumer wave (wg', mt) needs exactly the 128 same-mt
// producers' tags; it vector-polls all 128 in one 2-load __all loop, then
// sc1-loads the h fragments. No grid barrier, no broadcast chain.
__global__ __launch_bounds__(NTH, 1)
void lstm_mfma(const float* __restrict__ x,
               const float* __restrict__ Wf, const float* __restrict__ bfp,
               const float* __restrict__ Wi, const float* __restrict__ bip,
               const float* __restrict__ Wg, const float* __restrict__ bgp,
               const float* __restrict__ Wo, const float* __restrict__ bop,
               float* __restrict__ out,
               unsigned int* __restrict__ ws_u32)
{
    const int tid = threadIdx.x;
    const int l   = tid & 63;
    const int mt  = tid >> 6;              // wave = M-tile (batches mt*16..+15)
    const int wg  = blockIdx.x;
    const int j0  = wg * 4;

    const int n    = l & 15;               // output row (gate*4 + jc) in C cols
    const int khi  = l >> 4;               // k-group for A/B fragments

    unsigned int* const flags = ws_u32;    // (mt*128 + wg) * FLAG_STRIDE
    char* const hbase = (char*)ws_u32 + HBASE_OFF;

    // ---- load the 32 B-fragments (weights, bf16) into VGPRs, once ----------
    const float* Wn = (n < 8) ? ((n < 4) ? Wf : Wi) : ((n < 12) ? Wg : Wo);
    const float* wrow = Wn + (size_t)(j0 + (n & 3)) * KTOT + khi * 8;
    short8 Bfr[32];
    #pragma unroll
    for (int kt = 0; kt < 32; ++kt) {
        const float4 lo = *(const float4*)(wrow + kt * 32);
        const float4 hi = *(const float4*)(wrow + kt * 32 + 4);
        Bfr[kt] = cvt8(lo, hi);
    }
    const float biasn = ((n < 8) ? ((n < 4) ? bfp : bip)
                                 : ((n < 12) ? bgp : bop))[j0 + (n & 3)];

    // c-state: 4 values per jc-lane (lanes with (l>>2)&3 == 0)
    float cst0 = 0.f, cst1 = 0.f, cst2 = 0.f, cst3 = 0.f;

    float* const hx_out = out + (size_t)SEQ * BATCH * DH;
    float* const cx_out = hx_out + (size_t)BATCH * DH;

    // producer-side h-fragment coordinates (constant over t)
    const int kth    = wg >> 3;                         // h k-tile 0..15
    const int e_h    = (wg & 1) * 4 + (l & 3);          // elem 0..7 (jc-lanes)
    const int lane_f_base = ((wg & 7) >> 1) << 4;       // hi<<4

    // consumer-side poll pointers: the 128 same-mt producer tags
    const unsigned int* const f0p = flags + ((size_t)mt * 128 + l) * FLAG_STRIDE;
    const unsigned int* const f1p = f0p + (size_t)64 * FLAG_STRIDE;
    unsigned int* const my_flag = flags + ((size_t)mt * 128 + wg) * FLAG_STRIDE;

    const float* xrow_base = x + (size_t)(mt * 16 + (l & 15)) * DIN + khi * 8;

    for (int t = 0; t < SEQ; ++t) {
        f32x4 acc = {0.f, 0.f, 0.f, 0.f};

        // ---------- phase X: x[t] contribution (dependency-free) -----------
        {
            const float* xr = xrow_base + (size_t)t * BATCH * DIN;
            #pragma unroll
            for (int kt = 0; kt < 16; ++kt) {
                const float4 lo = *(const float4*)(xr + kt * 32);
                const float4 hi = *(const float4*)(xr + kt * 32 + 4);
                const short8 a = cvt8(lo, hi);
                acc = __builtin_amdgcn_mfma_f32_16x16x32_bf16(a, Bfr[kt], acc, 0, 0, 0);
            }
        }

        if (t > 0) {
            // ------ per-wave dependency wait: all 128 same-mt tags >= t ----
            const unsigned int target = (unsigned int)t;
            for (;;) {
                const unsigned int fa = ld_flag(f0p);
                const unsigned int fb = ld_flag(f1p);
                if (__all(fa >= target && fb >= target)) break;
                __builtin_amdgcn_s_sleep(2);
            }

            // ---------- phase H: h[t-1] via sc1 loads ----------------------
            const unsigned long long* hp =
                (const unsigned long long*)(hbase + ((t & 1) ^ 1) * HBUF_BYTES)
                + ((size_t)(mt * 16) * 64 + l) * 2;
            unsigned long long hv[32];
            #pragma unroll
            for (int kt = 0; kt < 16; ++kt) {
                hv[2 * kt]     = __hip_atomic_load(hp + kt * 128,     __ATOMIC_RELAXED,
                                                   __HIP_MEMORY_SCOPE_AGENT);
                hv[2 * kt + 1] = __hip_atomic_load(hp + kt * 128 + 1, __ATOMIC_RELAXED,
                                                   __HIP_MEMORY_SCOPE_AGENT);
            }
            #pragma unroll
            for (int kt = 0; kt < 16; ++kt) {
                union { unsigned long long u[2]; short8 v; } U;
                U.u[0] = hv[2 * kt];
                U.u[1] = hv[2 * kt + 1];
                acc = __builtin_amdgcn_mfma_f32_16x16x32_bf16(U.v, Bfr[16 + kt], acc, 0, 0, 0);
            }
        }

        // ---------- epilogue: gates, state update, stores ------------------
        const float p0 = acc[0] + biasn;
        const float p1 = acc[1] + biasn;
        const float p2 = acc[2] + biasn;
        const float p3 = acc[3] + biasn;

        const float i0 = __shfl_xor(p0, 4), g0 = __shfl_xor(p0, 8), o0 = __shfl_xor(p0, 12);
        const float i1 = __shfl_xor(p1, 4), g1 = __shfl_xor(p1, 8), o1 = __shfl_xor(p1, 12);
        const float i2 = __shfl_xor(p2, 4), g2 = __shfl_xor(p2, 8), o2 = __shfl_xor(p2, 12);
        const float i3 = __shfl_xor(p3, 4), g3 = __shfl_xor(p3, 8), o3 = __shfl_xor(p3, 12);

        if (((l >> 2) & 3) == 0) {          // jc-lanes: l&15 in 0..3
            const int jc = l & 3;
            const int j  = j0 + jc;
            const int b0 = mt * 16 + (l >> 4) * 4;   // q adds 0..3
            char* const wb = hbase + (t & 1) * HBUF_BYTES;

            float hq[4];
            cst0 = fmaf(sig_(p0), cst0, sig_(i0) * tanhf(g0)); hq[0] = sig_(o0) * tanhf(cst0);
            cst1 = fmaf(sig_(p1), cst1, sig_(i1) * tanhf(g1)); hq[1] = sig_(o1) * tanhf(cst1);
            cst2 = fmaf(sig_(p2), cst2, sig_(i2) * tanhf(g2)); hq[2] = sig_(o2) * tanhf(cst2);
            cst3 = fmaf(sig_(p3), cst3, sig_(i3) * tanhf(g3)); hq[3] = sig_(o3) * tanhf(cst3);

            #pragma unroll
            for (int q = 0; q < 4; ++q) {
                const int b = b0 + q;
                // h-fragment bf16 store for next step (sc1) — FIRST, so the
                // in-order vmcnt drain below covers them before the tag store
                unsigned short* hp_w = (unsigned short*)
                    (wb + (((size_t)(mt * 16 + kth) * 64
                            + (lane_f_base | (b & 15))) << 4) + e_h * 2);
                __hip_atomic_store(hp_w, f2bf(hq[q]), __ATOMIC_RELAXED,
                                   __HIP_MEMORY_SCOPE_AGENT);
                out[((size_t)t * BATCH + b) * DH + j] = hq[q];
            }
            if (t == SEQ - 1) {
                #pragma unroll
                for (int q = 0; q < 4; ++q) {
                    const int b = b0 + q;
                    hx_out[(size_t)b * DH + j] = hq[q];
                }
                cx_out[(size_t)b0 * DH + j]       = cst0;
                cx_out[(size_t)(b0 + 1) * DH + j] = cst1;
                cx_out[(size_t)(b0 + 2) * DH + j] = cst2;
                cx_out[(size_t)(b0 + 3) * DH + j] = cst3;
            }
        }

        if (t < SEQ - 1) {
            // drain all VMEM (h data stores included), then publish tag t+1
            asm volatile("s_waitcnt vmcnt(0)" ::: "memory");
            if (l == 0) st_flag(my_flag, (unsigned int)(t + 1));
        }
    }
}

extern "C" void kernel_launch(void* const* d_in, const int* in_sizes, int n_in,
                              void* d_out, int out_size, void* d_ws, size_t ws_size,
                              hipStream_t stream)
{
    const float* x  = (const float*)d_in[0];
    const float* Wf = (const float*)d_in[1];
    const float* bf = (const float*)d_in[2];
    const float* Wi = (const float*)d_in[3];
    const float* bi = (const float*)d_in[4];
    const float* Wg = (const float*)d_in[5];
    const float* bg = (const float*)d_in[6];
    const float* Wo = (const float*)d_in[7];
    const float* bo = (const float*)d_in[8];
    float* out = (float*)d_out;

    // Tag flags must be 0 at every launch (monotone within a call; ws is
    // poisoned 0xAA once and never re-poisoned). h buffers need no init:
    // consumers read them only after the matching tag is observed.
    hipMemsetAsync(d_ws, 0, HBASE_OFF, stream);

    lstm_mfma<<<NWG, NTH, 0, stream>>>(x, Wf, bf, Wi, bi, Wg, bg, Wo, bo,
                                       out, (unsigned int*)d_ws);
}

// Round 6
// 3637.645 us; speedup vs baseline: 1.3706x; 1.3259x over previous
//
#include <hip/hip_runtime.h>

#define SEQ   512
#define BATCH 64
#define DIN   512
#define DH    512
#define KTOT  1024
#define NWG   128
#define NTH   256
#define HBUF_BYTES 65536   // 4 mt * 16 kt * 64 lanes * 16 B

// ws layout (bytes):
//   [0, 65536)          per-(mt,wg) tag flags: offset (mt*128 + wg)*128
//   [65536, 65536+128K) h ping-pong buffers (2 x 64 KB)
#define HBASE_OFF 65536
#define FLAG_STRIDE 32   // uints (128 B)

typedef __attribute__((ext_vector_type(8))) short short8;   // 8 x bf16
typedef __attribute__((ext_vector_type(4))) float f32x4;

__device__ __forceinline__ float sig_(float v) { return 1.0f / (1.0f + __expf(-v)); }
// fast tanh via hardware exp: exact at +-inf saturation, ~1e-6 rel err
__device__ __forceinline__ float tanh_fast(float v) {
    const float e = __expf(2.0f * v);
    return 1.0f - 2.0f / (e + 1.0f);
}

// fp32 -> bf16 RNE (finite inputs), dependency-free
__device__ __forceinline__ unsigned int f2bf(float f) {
    unsigned int u = __float_as_uint(f);
    return (u + 0x7fffu + ((u >> 16) & 1u)) >> 16;
}

__device__ __forceinline__ short8 cvt8(float4 lo, float4 hi) {
    short8 r;
    r[0] = (short)f2bf(lo.x); r[1] = (short)f2bf(lo.y);
    r[2] = (short)f2bf(lo.z); r[3] = (short)f2bf(lo.w);
    r[4] = (short)f2bf(hi.x); r[5] = (short)f2bf(hi.y);
    r[6] = (short)f2bf(hi.z); r[7] = (short)f2bf(hi.w);
    return r;
}

__device__ __forceinline__ unsigned int ld_flag(const unsigned int* p) {
    return __hip_atomic_load(p, __ATOMIC_RELAXED, __HIP_MEMORY_SCOPE_AGENT);
}
__device__ __forceinline__ void st_flag(unsigned int* p, unsigned int v) {
    __hip_atomic_store(p, v, __ATOMIC_RELAXED, __HIP_MEMORY_SCOPE_AGENT);
}

// Persistent MFMA LSTM, round 6: r5 dataflow + coalesced producer stores.
// Per step each jc-lane transposes its 4 h values (4x4 lane-group transpose)
// so the h publish is ONE 8B sc1 store/lane and the out write is ONE float4
// store/lane. Drain order: h-store -> vmcnt(0) -> tag -> out (off-path).
__global__ __launch_bounds__(NTH, 1)
void lstm_mfma(const float* __restrict__ x,
               const float* __restrict__ Wf, const float* __restrict__ bfp,
               const float* __restrict__ Wi, const float* __restrict__ bip,
               const float* __restrict__ Wg, const float* __restrict__ bgp,
               const float* __restrict__ Wo, const float* __restrict__ bop,
               float* __restrict__ out,
               unsigned int* __restrict__ ws_u32)
{
    const int tid = threadIdx.x;
    const int l   = tid & 63;
    const int mt  = tid >> 6;              // wave = M-tile (batches mt*16..+15)
    const int wg  = blockIdx.x;
    const int j0  = wg * 4;

    const int n    = l & 15;               // output row (gate*4 + jc) in C cols
    const int khi  = l >> 4;               // k-group for A/B fragments

    unsigned int* const flags = ws_u32;    // (mt*128 + wg) * FLAG_STRIDE
    char* const hbase = (char*)ws_u32 + HBASE_OFF;

    // ---- load the 32 B-fragments (weights, bf16) into VGPRs, once ----------
    const float* Wn = (n < 8) ? ((n < 4) ? Wf : Wi) : ((n < 12) ? Wg : Wo);
    const float* wrow = Wn + (size_t)(j0 + (n & 3)) * KTOT + khi * 8;
    short8 Bfr[32];
    #pragma unroll
    for (int kt = 0; kt < 32; ++kt) {
        const float4 lo = *(const float4*)(wrow + kt * 32);
        const float4 hi = *(const float4*)(wrow + kt * 32 + 4);
        Bfr[kt] = cvt8(lo, hi);
    }
    const float biasn = ((n < 8) ? ((n < 4) ? bfp : bip)
                                 : ((n < 12) ? bgp : bop))[j0 + (n & 3)];

    // c-state: 4 values per jc-lane (lanes with (l>>2)&3 == 0)
    float cst0 = 0.f, cst1 = 0.f, cst2 = 0.f, cst3 = 0.f;

    float* const hx_out = out + (size_t)SEQ * BATCH * DH;
    float* const cx_out = hx_out + (size_t)BATCH * DH;

    // producer-side h-fragment coordinates (constant over t)
    const int kth         = wg >> 3;                    // h k-tile 0..15
    const int lane_f_base = ((wg & 7) >> 1) << 4;       // hi<<4
    const int half8       = (wg & 1) * 8;               // byte offset of j-quad

    // consumer-side poll pointers: the 128 same-mt producer tags
    const unsigned int* const f0p = flags + ((size_t)mt * 128 + l) * FLAG_STRIDE;
    const unsigned int* const f1p = f0p + (size_t)64 * FLAG_STRIDE;
    unsigned int* const my_flag = flags + ((size_t)mt * 128 + wg) * FLAG_STRIDE;

    const float* xrow_base = x + (size_t)(mt * 16 + (l & 15)) * DIN + khi * 8;

    for (int t = 0; t < SEQ; ++t) {
        f32x4 acc = {0.f, 0.f, 0.f, 0.f};

        // ---------- phase X: x[t] contribution (dependency-free) -----------
        {
            const float* xr = xrow_base + (size_t)t * BATCH * DIN;
            #pragma unroll
            for (int kt = 0; kt < 16; ++kt) {
                const float4 lo = *(const float4*)(xr + kt * 32);
                const float4 hi = *(const float4*)(xr + kt * 32 + 4);
                const short8 a = cvt8(lo, hi);
                acc = __builtin_amdgcn_mfma_f32_16x16x32_bf16(a, Bfr[kt], acc, 0, 0, 0);
            }
        }

        if (t > 0) {
            // ------ per-wave dependency wait: all 128 same-mt tags >= t ----
            const unsigned int target = (unsigned int)t;
            for (;;) {
                const unsigned int fa = ld_flag(f0p);
                const unsigned int fb = ld_flag(f1p);
                if (__all(fa >= target && fb >= target)) break;
                __builtin_amdgcn_s_sleep(1);
            }

            // ---------- phase H: h[t-1] via sc1 loads ----------------------
            const unsigned long long* hp =
                (const unsigned long long*)(hbase + ((t & 1) ^ 1) * HBUF_BYTES)
                + ((size_t)(mt * 16) * 64 + l) * 2;
            unsigned long long hv[32];
            #pragma unroll
            for (int kt = 0; kt < 16; ++kt) {
                hv[2 * kt]     = __hip_atomic_load(hp + kt * 128,     __ATOMIC_RELAXED,
                                                   __HIP_MEMORY_SCOPE_AGENT);
                hv[2 * kt + 1] = __hip_atomic_load(hp + kt * 128 + 1, __ATOMIC_RELAXED,
                                                   __HIP_MEMORY_SCOPE_AGENT);
            }
            #pragma unroll
            for (int kt = 0; kt < 16; ++kt) {
                union { unsigned long long u[2]; short8 v; } U;
                U.u[0] = hv[2 * kt];
                U.u[1] = hv[2 * kt + 1];
                acc = __builtin_amdgcn_mfma_f32_16x16x32_bf16(U.v, Bfr[16 + kt], acc, 0, 0, 0);
            }
        }

        // ---------- epilogue: gates, state update, stores ------------------
        const float p0 = acc[0] + biasn;
        const float p1 = acc[1] + biasn;
        const float p2 = acc[2] + biasn;
        const float p3 = acc[3] + biasn;

        const float i0 = __shfl_xor(p0, 4), g0 = __shfl_xor(p0, 8), o0 = __shfl_xor(p0, 12);
        const float i1 = __shfl_xor(p1, 4), g1 = __shfl_xor(p1, 8), o1 = __shfl_xor(p1, 12);
        const float i2 = __shfl_xor(p2, 4), g2 = __shfl_xor(p2, 8), o2 = __shfl_xor(p2, 12);
        const float i3 = __shfl_xor(p3, 4), g3 = __shfl_xor(p3, 8), o3 = __shfl_xor(p3, 12);

        const bool active = ((l >> 2) & 3) == 0;   // jc-lanes: l&15 in 0..3
        float v0 = 0.f, v1 = 0.f, v2 = 0.f, v3 = 0.f;   // transposed h quad
        int   bT = 0;                                    // this lane's batch

        if (active) {
            float hq0, hq1, hq2, hq3;
            cst0 = fmaf(sig_(p0), cst0, sig_(i0) * tanh_fast(g0)); hq0 = sig_(o0) * tanh_fast(cst0);
            cst1 = fmaf(sig_(p1), cst1, sig_(i1) * tanh_fast(g1)); hq1 = sig_(o1) * tanh_fast(cst1);
            cst2 = fmaf(sig_(p2), cst2, sig_(i2) * tanh_fast(g2)); hq2 = sig_(o2) * tanh_fast(cst2);
            cst3 = fmaf(sig_(p3), cst3, sig_(i3) * tanh_fast(g3)); hq3 = sig_(o3) * tanh_fast(cst3);

            // 4x4 transpose within each 4-lane group: afterwards lane (g,p)
            // holds h[b = mt*16+g*4+p][j0..j0+3] in v0..v3.
            const int src = l & 48;   // group base lane
            const int jc  = l & 3;
            #pragma unroll
            for (int q = 0; q < 4; ++q) {
                const float hqq = (q == 0) ? hq0 : (q == 1) ? hq1 : (q == 2) ? hq2 : hq3;
                #pragma unroll
                for (int jj = 0; jj < 4; ++jj) {
                    const float tsh = __shfl(hqq, src + jj);
                    if (jc == q) {
                        if (jj == 0) v0 = tsh; else if (jj == 1) v1 = tsh;
                        else if (jj == 2) v2 = tsh; else v3 = tsh;
                    }
                }
            }
            bT = mt * 16 + ((l >> 4) << 2) + jc;

            if (t < SEQ - 1) {
                // ---- ONE 8B sc1 store per lane: packed bf16 j-quad --------
                const unsigned long long pk =
                    (unsigned long long)(f2bf(v0) | (f2bf(v1) << 16))
                    | ((unsigned long long)(f2bf(v2) | (f2bf(v3) << 16)) << 32);
                char* const wb = hbase + (t & 1) * HBUF_BYTES;
                unsigned long long* hp_w = (unsigned long long*)
                    (wb + (((size_t)(mt * 16 + kth) * 64
                            + (lane_f_base | (bT & 15))) << 4) + half8);
                __hip_atomic_store(hp_w, pk, __ATOMIC_RELAXED,
                                   __HIP_MEMORY_SCOPE_AGENT);
            }
        }

        if (t < SEQ - 1) {
            // drain h stores, publish tag, THEN write out (off critical path)
            asm volatile("s_waitcnt vmcnt(0)" ::: "memory");
            if (l == 0) st_flag(my_flag, (unsigned int)(t + 1));
        }

        if (active) {
            const float4 ov = make_float4(v0, v1, v2, v3);
            *(float4*)(out + ((size_t)t * BATCH + bT) * DH + j0) = ov;
            if (t == SEQ - 1) {
                *(float4*)(hx_out + (size_t)bT * DH + j0) = ov;
                const int b0 = mt * 16 + ((l >> 4) << 2);
                const int j  = j0 + (l & 3);
                cx_out[(size_t)b0 * DH + j]       = cst0;
                cx_out[(size_t)(b0 + 1) * DH + j] = cst1;
                cx_out[(size_t)(b0 + 2) * DH + j] = cst2;
                cx_out[(size_t)(b0 + 3) * DH + j] = cst3;
            }
        }
    }
}

extern "C" void kernel_launch(void* const* d_in, const int* in_sizes, int n_in,
                              void* d_out, int out_size, void* d_ws, size_t ws_size,
                              hipStream_t stream)
{
    const float* x  = (const float*)d_in[0];
    const float* Wf = (const float*)d_in[1];
    const float* bf = (const float*)d_in[2];
    const float* Wi = (const float*)d_in[3];
    const float* bi = (const float*)d_in[4];
    const float* Wg = (const float*)d_in[5];
    const float* bg = (const float*)d_in[6];
    const float* Wo = (const float*)d_in[7];
    const float* bo = (const float*)d_in[8];
    float* out = (float*)d_out;

    // Tag flags must be 0 at every launch (monotone within a call; ws is
    // poisoned 0xAA once and never re-poisoned). h buffers need no init:
    // consumers read them only after the matching tag is observed.
    hipMemsetAsync(d_ws, 0, HBASE_OFF, stream);

    lstm_mfma<<<NWG, NTH, 0, stream>>>(x, Wf, bf, Wi, bi, Wg, bg, Wo, bo,
                                       out, (unsigned int*)d_ws);
}